// Round 2
// baseline (271.317 us; speedup 1.0000x reference)
//
#include <hip/hip_runtime.h>
#include <stdint.h>

typedef __attribute__((ext_vector_type(8))) short  bf16x8;
typedef __attribute__((ext_vector_type(4))) short  short4v;
typedef __attribute__((ext_vector_type(4))) float  f32x4;
typedef __attribute__((ext_vector_type(4))) float  float4v;

__device__ __forceinline__ short f2bf(float f) {
  union { float f; uint32_t u; } c; c.f = f;
  uint32_t u = c.u;
  uint32_t r = (u + 0x7FFFu + ((u >> 16) & 1u)) >> 16;
  return (short)(uint16_t)r;
}

__device__ __forceinline__ void gload_lds16(const void* g, void* l) {
  __builtin_amdgcn_global_load_lds(
      (const __attribute__((address_space(1))) void*)g,
      (__attribute__((address_space(3))) void*)l, 16, 0, 0);
}

// ---------------- f32 -> bf16 (vectorized, 4 elems/thread) ----------------
__global__ __launch_bounds__(256) void k_f32_to_bf16(
    const float* __restrict__ in, short* __restrict__ out, int n4) {
  int i = blockIdx.x * 256 + threadIdx.x;
  if (i >= n4) return;
  float4v v = *(const float4v*)(in + (size_t)i * 4);
  short4v o;
  o.x = f2bf(v.x); o.y = f2bf(v.y); o.z = f2bf(v.z); o.w = f2bf(v.w);
  *(short4v*)(out + (size_t)i * 4) = o;
}

// ------------- transpose f32[R][C] -> bf16[C][R] (64x64 LDS tiles) -------------
__global__ __launch_bounds__(256) void k_transpose_bf16(
    const float* __restrict__ in, short* __restrict__ out, int R, int C) {
  __shared__ short tile[64][65];
  int bc = blockIdx.x * 64, br = blockIdx.y * 64;
  int tc = threadIdx.x & 63, tr = threadIdx.x >> 6;  // tr 0..3
#pragma unroll
  for (int i = 0; i < 64; i += 4)
    tile[tc][tr + i] = f2bf(in[(size_t)(br + tr + i) * C + bc + tc]);
  __syncthreads();
#pragma unroll
  for (int i = 0; i < 64; i += 4)
    out[(size_t)(bc + tr + i) * R + br + tc] = tile[tr + i][tc];
}

// ------------- GEMM: C[M][N] = A[M][K](bf16) * BT[N][K]^T + bias ---------------
// m97 structure: 128x128 tile, BK=32, 4 waves (2x2), 4x4 16x16x32 frags/wave.
template <bool F32OUT>
__global__ __launch_bounds__(256) void k_gemm_bt(
    const short* __restrict__ A, const short* __restrict__ BT,
    const float* __restrict__ bias, void* __restrict__ Cout,
    int M, int N, int K) {
  __shared__ short As[128][32];
  __shared__ short Bs[128][32];
  const int tid = threadIdx.x;
  const int w = tid >> 6, l = tid & 63;
  const int fr = l & 15, fg = l >> 4;
  const int nbn = N >> 7;
  const int bm = blockIdx.x / nbn, bn = blockIdx.x % nbn;
  const size_t brow = (size_t)bm << 7;
  const int bcol = bn << 7;
  const int wr = w >> 1, wc = w & 1;

  const int lrow = l >> 2;        // 0..15 row within 16-row chunk
  const int lk = (l & 3) << 3;    // k-part 0,8,16,24

  const short* Arow0 = A + (brow + (size_t)(w * 32 + lrow)) * K + lk;
  const short* Arow1 = Arow0 + (size_t)16 * K;
  const short* Brow0 = BT + ((size_t)(bcol + w * 32 + lrow)) * K + lk;
  const short* Brow1 = Brow0 + (size_t)16 * K;
  char* asd0 = (char*)&As[0][0] + (w * 2) * 1024;
  char* asd1 = asd0 + 1024;
  char* bsd0 = (char*)&Bs[0][0] + (w * 2) * 1024;
  char* bsd1 = bsd0 + 1024;

  f32x4 acc[4][4] = {};

  for (int kt = 0; kt < K; kt += 32) {
    gload_lds16(Arow0 + kt, asd0);
    gload_lds16(Arow1 + kt, asd1);
    gload_lds16(Brow0 + kt, bsd0);
    gload_lds16(Brow1 + kt, bsd1);
    __syncthreads();
    bf16x8 af[4], bfv[4];
#pragma unroll
    for (int m = 0; m < 4; ++m)
      af[m] = *(const bf16x8*)&As[wr * 64 + m * 16 + fr][fg * 8];
#pragma unroll
    for (int n = 0; n < 4; ++n)
      bfv[n] = *(const bf16x8*)&Bs[wc * 64 + n * 16 + fr][fg * 8];
#pragma unroll
    for (int m = 0; m < 4; ++m)
#pragma unroll
      for (int n = 0; n < 4; ++n)
        acc[m][n] = __builtin_amdgcn_mfma_f32_16x16x32_bf16(
            af[m], bfv[n], acc[m][n], 0, 0, 0);
    __syncthreads();
  }

#pragma unroll
  for (int n = 0; n < 4; ++n) {
    int col = bcol + wc * 64 + n * 16 + fr;
    float bv = bias[col];
#pragma unroll
    for (int m = 0; m < 4; ++m) {
      size_t row = brow + (size_t)(wr * 64 + m * 16 + fg * 4);
#pragma unroll
      for (int r = 0; r < 4; ++r) {
        float v = acc[m][n][r] + bv;
        if (F32OUT)
          ((float*)Cout)[(row + r) * (size_t)N + col] = v;
        else
          ((short*)Cout)[(row + r) * (size_t)N + col] = f2bf(v);
      }
    }
  }
}

// ---------------- fused anti-causal flash attention (keep k >= q) ----------------
// qkv bf16 [B*S][3072]; head h: Q cols h*64, K cols 1024+h*64, V cols 2048+h*64.
// Block handles the BALANCED PAIR of q-tiles (pair, 15-pair) for one (b,h):
// tiles for q-tile (15-pair) are a subset of those for (pair), so one k-loop
// stages K/V once and feeds both. Every block = exactly 17 compute-steps.
__global__ __launch_bounds__(256, 4) void k_attn(
    const short* __restrict__ qkv, short* __restrict__ outc, int Bn, int S) {
  __shared__ short Ks[64][64];      // XOR-swizzled 16B slots within 128B rows
  __shared__ short Vt[64][72];      // V^T, padded pitch
  __shared__ short Pl[4][16][72];   // per-wave P [16 q][64 k], padded pitch

  const int tid = threadIdx.x;
  const int w = tid >> 6, l = tid & 63;
  const int fr = l & 15, fg = l >> 4;

  // XCD swizzle: all 8 pair-blocks of one (b,h) on one XCD (K/V L2-resident)
  const int xcd = blockIdx.x & 7;
  const int idx = blockIdx.x >> 3;       // 0..127
  const int bh = xcd * 16 + (idx >> 3);  // 0..127
  const int pair = idx & 7;
  const int h = bh & 15, b = bh >> 4;

  const int tqa = pair, tqb = 15 - pair;  // tqa in 0..7, tqb in 8..15
  const int q0a = tqa << 6, q0b = tqb << 6;

  const size_t rowbase = (size_t)b * S;
  const int qcola = q0a + w * 16 + fr;
  const int qcolb = q0b + w * 16 + fr;

  bf16x8 qfa[2], qfb[2];
  {
    const short* qp = qkv + (rowbase + qcola) * 3072 + h * 64 + fg * 8;
    qfa[0] = *(const bf16x8*)qp;
    qfa[1] = *(const bf16x8*)(qp + 32);
    const short* qq = qkv + (rowbase + qcolb) * 3072 + h * 64 + fg * 8;
    qfb[0] = *(const bf16x8*)qq;
    qfb[1] = *(const bf16x8*)(qq + 32);
  }

  f32x4 oa[4] = {}, ob[4] = {};
  float ma = -3.0e38f, la = 0.0f;
  float mb = -3.0e38f, lb = 0.0f;

  const short* Kbase = qkv + rowbase * 3072 + 1024 + h * 64;
  const short* Vbase = qkv + rowbase * 3072 + 2048 + h * 64;
  const float C2 = 0.04508422f;  // log2(e) / sqrt(1024)

  // one softmax+PV step for one q-tile against the staged K/V tile
  auto process = [&](const bf16x8* qf, f32x4* o, float& m2, float& ls,
                     int qcol, int k0, bool masked) {
    f32x4 st[4];
#pragma unroll
    for (int kb = 0; kb < 4; ++kb) {
      f32x4 z = {0.f, 0.f, 0.f, 0.f};
      int row = kb * 16 + fr;
      int sw = row & 7;
      bf16x8 kf0 = *(const bf16x8*)&Ks[row][(fg ^ sw) << 3];
      bf16x8 kf1 = *(const bf16x8*)&Ks[row][((4 + fg) ^ sw) << 3];
      z = __builtin_amdgcn_mfma_f32_16x16x32_bf16(kf0, qf[0], z, 0, 0, 0);
      z = __builtin_amdgcn_mfma_f32_16x16x32_bf16(kf1, qf[1], z, 0, 0, 0);
      st[kb] = z;
    }
    float p[16];
#pragma unroll
    for (int kb = 0; kb < 4; ++kb)
#pragma unroll
      for (int r = 0; r < 4; ++r) {
        float s = st[kb][r] * C2;  // base-2 domain: exp2(s) == exp(raw/32)
        if (masked) {
          int kg = k0 + kb * 16 + fg * 4 + r;
          s = (kg < qcol) ? -3.0e38f : s;
        }
        p[kb * 4 + r] = s;
      }
    // max3-friendly reduce
    float pm = fmaxf(fmaxf(p[0], p[1]), p[2]);
    pm = fmaxf(fmaxf(pm, p[3]), p[4]);
    pm = fmaxf(fmaxf(pm, p[5]), p[6]);
    pm = fmaxf(fmaxf(pm, p[7]), p[8]);
    pm = fmaxf(fmaxf(pm, p[9]), p[10]);
    pm = fmaxf(fmaxf(pm, p[11]), p[12]);
    pm = fmaxf(fmaxf(pm, p[13]), p[14]);
    pm = fmaxf(pm, p[15]);
    pm = fmaxf(pm, __shfl_xor(pm, 16, 64));
    pm = fmaxf(pm, __shfl_xor(pm, 32, 64));

    bool skip = __all(pm - m2 <= 8.0f);  // defer-max (T13): P bounded by 2^8
    float mnew = skip ? m2 : fmaxf(m2, pm);
    float psum = 0.f;
#pragma unroll
    for (int i = 0; i < 16; ++i) {
      float e = exp2f(p[i] - mnew);
      p[i] = e;
      psum += e;
    }
    psum += __shfl_xor(psum, 16, 64);
    psum += __shfl_xor(psum, 32, 64);
    if (skip) {
      ls += psum;
    } else {
      float scl = exp2f(m2 - mnew);
      ls = ls * scl + psum;
      m2 = mnew;
#pragma unroll
      for (int r = 0; r < 4; ++r) {
        float so = __shfl(scl, fg * 4 + r, 64);
#pragma unroll
        for (int f = 0; f < 4; ++f) o[f][r] *= so;
      }
    }
    // P -> bf16 -> per-wave LDS (same-wave RAW: DS in-order)
#pragma unroll
    for (int kb = 0; kb < 4; ++kb) {
      short4v pw = {f2bf(p[kb * 4 + 0]), f2bf(p[kb * 4 + 1]),
                    f2bf(p[kb * 4 + 2]), f2bf(p[kb * 4 + 3])};
      *(short4v*)&Pl[w][fr][kb * 16 + fg * 4] = pw;
    }
    bf16x8 pa0 = *(const bf16x8*)&Pl[w][fr][fg * 8];
    bf16x8 pa1 = *(const bf16x8*)&Pl[w][fr][32 + fg * 8];
#pragma unroll
    for (int f = 0; f < 4; ++f) {
      bf16x8 v0 = *(const bf16x8*)&Vt[f * 16 + fr][fg * 8];
      bf16x8 v1 = *(const bf16x8*)&Vt[f * 16 + fr][32 + fg * 8];
      o[f] = __builtin_amdgcn_mfma_f32_16x16x32_bf16(pa0, v0, o[f], 0, 0, 0);
      o[f] = __builtin_amdgcn_mfma_f32_16x16x32_bf16(pa1, v1, o[f], 0, 0, 0);
    }
  };

  for (int kt = tqa; kt < 16; ++kt) {
    const int k0 = kt << 6;
    // stage K via global_load_lds, source pre-swizzled so LDS slot = octet ^ (row&7)
    {
      int r8 = l >> 3;
      int slot = l & 7;
#pragma unroll
      for (int j = 0; j < 2; ++j) {
        int ch = w * 2 + j;
        int row = ch * 8 + r8;
        int d = ((slot ^ (row & 7)) << 3);
        gload_lds16(Kbase + (size_t)(k0 + row) * 3072 + d,
                    (char*)&Ks[0][0] + ch * 1024);
      }
    }
    // stage V transposed (reg 4x4 transpose)
    {
      int kb = (tid & 15) << 2;
      int db = (tid >> 4) << 2;
      const short* vp = Vbase + (size_t)(k0 + kb) * 3072 + db;
      short4v r0 = *(const short4v*)(vp);
      short4v r1 = *(const short4v*)(vp + 3072);
      short4v r2 = *(const short4v*)(vp + 2 * 3072);
      short4v r3 = *(const short4v*)(vp + 3 * 3072);
      short4v c0 = {r0.x, r1.x, r2.x, r3.x};
      short4v c1 = {r0.y, r1.y, r2.y, r3.y};
      short4v c2 = {r0.z, r1.z, r2.z, r3.z};
      short4v c3 = {r0.w, r1.w, r2.w, r3.w};
      *(short4v*)&Vt[db + 0][kb] = c0;
      *(short4v*)&Vt[db + 1][kb] = c1;
      *(short4v*)&Vt[db + 2][kb] = c2;
      *(short4v*)&Vt[db + 3][kb] = c3;
    }
    __syncthreads();

    process(qfa, oa, ma, la, qcola, k0, kt == tqa);
    if (kt >= tqb) process(qfb, ob, mb, lb, qcolb, k0, kt == tqb);

    __syncthreads();
  }

  // normalize + store bf16 (both q-tiles)
#pragma unroll
  for (int r = 0; r < 4; ++r) {
    float da = __shfl(la, fg * 4 + r, 64);
    float db_ = __shfl(lb, fg * 4 + r, 64);
    float ia = 1.0f / da, ib = 1.0f / db_;
    size_t ra = rowbase + (size_t)(q0a + w * 16 + fg * 4 + r);
    size_t rb = rowbase + (size_t)(q0b + w * 16 + fg * 4 + r);
    short* opa = outc + ra * 1024 + h * 64 + fr;
    short* opb = outc + rb * 1024 + h * 64 + fr;
#pragma unroll
    for (int f = 0; f < 4; ++f) {
      opa[f * 16] = f2bf(oa[f][r] * ia);
      opb[f * 16] = f2bf(ob[f][r] * ib);
    }
  }
}

extern "C" void kernel_launch(void* const* d_in, const int* in_sizes, int n_in,
                              void* d_out, int out_size, void* d_ws,
                              size_t ws_size, hipStream_t stream) {
  const float* x = (const float*)d_in[0];
  const float* Wc = (const float*)d_in[1];
  const float* bc = (const float*)d_in[2];
  const float* Wo = (const float*)d_in[3];
  const float* bo = (const float*)d_in[4];
  float* out = (float*)d_out;

  const int Bn = 8, S = 1024, D = 1024;
  const int M = Bn * S;  // 8192

  char* ws = (char*)d_ws;
  short* xb  = (short*)(ws);                               // 16 MB
  short* wct = (short*)(ws + (size_t)16 * 1024 * 1024);    // 6 MB  [3072][1024]
  short* wot = (short*)(ws + (size_t)22 * 1024 * 1024);    // 2 MB  [1024][1024]
  short* qkv = (short*)(ws + (size_t)24 * 1024 * 1024);    // 48 MB [8192][3072]
  short* cat = (short*)(ws + (size_t)72 * 1024 * 1024);    // 16 MB [8192][1024]

  k_f32_to_bf16<<<(M * D / 4 + 255) / 256, 256, 0, stream>>>(x, xb, M * D / 4);
  {
    dim3 g(3 * D / 64, D / 64);
    k_transpose_bf16<<<g, 256, 0, stream>>>(Wc, wct, D, 3 * D);
  }
  {
    dim3 g(D / 64, D / 64);
    k_transpose_bf16<<<g, 256, 0, stream>>>(Wo, wot, D, D);
  }
  k_gemm_bt<false><<<(M / 128) * (3 * D / 128), 256, 0, stream>>>(
      xb, wct, bc, qkv, M, 3 * D, D);
  k_attn<<<Bn * 16 * 8, 256, 0, stream>>>(qkv, cat, Bn, S);
  k_gemm_bt<true><<<(M / 128) * (D / 128), 256, 0, stream>>>(
      cat, wot, bo, out, M, D, D);
}

// Round 4
// 195.154 us; speedup vs baseline: 1.3903x; 1.3903x over previous
//
#include <hip/hip_runtime.h>
#include <stdint.h>

typedef __attribute__((ext_vector_type(8))) short  bf16x8;
typedef __attribute__((ext_vector_type(4))) short  short4v;
typedef __attribute__((ext_vector_type(4))) float  f32x4;
typedef __attribute__((ext_vector_type(4))) float  float4v;

__device__ __forceinline__ short f2bf(float f) {
  union { float f; uint32_t u; } c; c.f = f;
  uint32_t u = c.u;
  uint32_t r = (u + 0x7FFFu + ((u >> 16) & 1u)) >> 16;
  return (short)(uint16_t)r;
}

__device__ __forceinline__ void gload_lds16(const void* g, void* l) {
  __builtin_amdgcn_global_load_lds(
      (const __attribute__((address_space(1))) void*)g,
      (__attribute__((address_space(3))) void*)l, 16, 0, 0);
}

// ---------------- f32 -> bf16 (vectorized, 4 elems/thread) ----------------
__global__ __launch_bounds__(256) void k_f32_to_bf16(
    const float* __restrict__ in, short* __restrict__ out, int n4) {
  int i = blockIdx.x * 256 + threadIdx.x;
  if (i >= n4) return;
  float4v v = *(const float4v*)(in + (size_t)i * 4);
  short4v o;
  o.x = f2bf(v.x); o.y = f2bf(v.y); o.z = f2bf(v.z); o.w = f2bf(v.w);
  *(short4v*)(out + (size_t)i * 4) = o;
}

// ------------- transpose f32[R][C] -> bf16[C][R] (64x64 LDS tiles) -------------
__global__ __launch_bounds__(256) void k_transpose_bf16(
    const float* __restrict__ in, short* __restrict__ out, int R, int C) {
  __shared__ short tile[64][65];
  int bc = blockIdx.x * 64, br = blockIdx.y * 64;
  int tc = threadIdx.x & 63, tr = threadIdx.x >> 6;  // tr 0..3
#pragma unroll
  for (int i = 0; i < 64; i += 4)
    tile[tc][tr + i] = f2bf(in[(size_t)(br + tr + i) * C + bc + tc]);
  __syncthreads();
#pragma unroll
  for (int i = 0; i < 64; i += 4)
    out[(size_t)(bc + tr + i) * R + br + tc] = tile[tr + i][tc];
}

// ------------- GEMM: C[M][N] = A[M][K](bf16) * BT[N][K]^T + bias ---------------
template <bool F32OUT>
__global__ __launch_bounds__(256) void k_gemm_bt(
    const short* __restrict__ A, const short* __restrict__ BT,
    const float* __restrict__ bias, void* __restrict__ Cout,
    int M, int N, int K) {
  __shared__ short As[128][32];
  __shared__ short Bs[128][32];
  const int tid = threadIdx.x;
  const int w = tid >> 6, l = tid & 63;
  const int fr = l & 15, fg = l >> 4;
  const int nbn = N >> 7;
  const int bm = blockIdx.x / nbn, bn = blockIdx.x % nbn;
  const size_t brow = (size_t)bm << 7;
  const int bcol = bn << 7;
  const int wr = w >> 1, wc = w & 1;

  const int lrow = l >> 2;
  const int lk = (l & 3) << 3;

  const short* Arow0 = A + (brow + (size_t)(w * 32 + lrow)) * K + lk;
  const short* Arow1 = Arow0 + (size_t)16 * K;
  const short* Brow0 = BT + ((size_t)(bcol + w * 32 + lrow)) * K + lk;
  const short* Brow1 = Brow0 + (size_t)16 * K;
  char* asd0 = (char*)&As[0][0] + (w * 2) * 1024;
  char* asd1 = asd0 + 1024;
  char* bsd0 = (char*)&Bs[0][0] + (w * 2) * 1024;
  char* bsd1 = bsd0 + 1024;

  f32x4 acc[4][4] = {};

  for (int kt = 0; kt < K; kt += 32) {
    gload_lds16(Arow0 + kt, asd0);
    gload_lds16(Arow1 + kt, asd1);
    gload_lds16(Brow0 + kt, bsd0);
    gload_lds16(Brow1 + kt, bsd1);
    __syncthreads();
    bf16x8 af[4], bfv[4];
#pragma unroll
    for (int m = 0; m < 4; ++m)
      af[m] = *(const bf16x8*)&As[wr * 64 + m * 16 + fr][fg * 8];
#pragma unroll
    for (int n = 0; n < 4; ++n)
      bfv[n] = *(const bf16x8*)&Bs[wc * 64 + n * 16 + fr][fg * 8];
#pragma unroll
    for (int m = 0; m < 4; ++m)
#pragma unroll
      for (int n = 0; n < 4; ++n)
        acc[m][n] = __builtin_amdgcn_mfma_f32_16x16x32_bf16(
            af[m], bfv[n], acc[m][n], 0, 0, 0);
    __syncthreads();
  }

#pragma unroll
  for (int n = 0; n < 4; ++n) {
    int col = bcol + wc * 64 + n * 16 + fr;
    float bv = bias[col];
#pragma unroll
    for (int m = 0; m < 4; ++m) {
      size_t row = brow + (size_t)(wr * 64 + m * 16 + fg * 4);
#pragma unroll
      for (int r = 0; r < 4; ++r) {
        float v = acc[m][n][r] + bv;
        if (F32OUT)
          ((float*)Cout)[(row + r) * (size_t)N + col] = v;
        else
          ((short*)Cout)[(row + r) * (size_t)N + col] = f2bf(v);
      }
    }
  }
}

// ---------------- fused anti-causal flash attention (keep k >= q) ----------------
// qkv bf16 [B*S][3072]; head h: Q cols h*64, K cols 1024+h*64, V cols 2048+h*64.
// One block = one (b,h,q-tile of 64). KVBLK=128. 4 waves x 16 q-rows.
// Swapped QK^T (mfma(K,Q)) puts P[q=fr][k=16kb+fg*4+r] in-lane. PV reuses
// mfma_16x16x32 with a k-PERMUTED operand pair: A = {P[kb],P[kb+1]} slots,
// B = V^T read in the same permuted order (permuting k on both sides is a
// no-op on the result). -> zero cross-lane P movement, no P LDS.
// blockIdx = tq*128 + bh: long blocks (tq=0) first (LPT), bh&7 pins XCD/L2.
__global__ __launch_bounds__(256) void k_attn(
    const short* __restrict__ qkv, short* __restrict__ outc, int Bn, int S) {
  __shared__ short Ks[128][64];   // 16B slots XOR-swizzled within 128B rows
  __shared__ short Vt[64][136];   // V^T, padded pitch

  const int tid = threadIdx.x;
  const int w = tid >> 6, l = tid & 63;
  const int fr = l & 15, fg = l >> 4;

  const int tq = blockIdx.x >> 7;        // 0..15, longest work first
  const int bh = blockIdx.x & 127;
  const int h = bh & 15, b = bh >> 4;
  const int q0 = tq << 6;

  const size_t rowbase = (size_t)b * S;
  const int qcol = q0 + w * 16 + fr;     // this lane's q-row (as S^T column)

  bf16x8 qf[2];
  {
    const short* qp = qkv + (rowbase + qcol) * 3072 + h * 64 + fg * 8;
    qf[0] = *(const bf16x8*)qp;
    qf[1] = *(const bf16x8*)(qp + 32);
  }

  f32x4 o[4] = {};
  float m2 = -3.0e38f, ls = 0.0f;

  const short* Kbase = qkv + rowbase * 3072 + 1024 + h * 64;
  const short* Vbase = qkv + rowbase * 3072 + 2048 + h * 64;
  const float C2 = 0.04508422f;  // log2(e)/sqrt(1024): exp2(s*C2)==exp(s/32)

  const int c0 = tq >> 1;
  for (int c = c0; c < 8; ++c) {
    const int k0 = c << 7;
    // stage K: 128 rows x 128B, source pre-swizzled so LDS slot = octet^(row&7)
    {
      int r8 = l >> 3, slot = l & 7;
#pragma unroll
      for (int j = 0; j < 4; ++j) {
        int ch = w * 4 + j;
        int row = ch * 8 + r8;
        int d = (slot ^ (row & 7)) << 3;
        gload_lds16(Kbase + (size_t)(k0 + row) * 3072 + d,
                    (char*)&Ks[0][0] + ch * 1024);
      }
    }
    // stage V^T: 128 k x 64 d (reg 4x4 transpose, two k-halves)
    {
      int db = (tid >> 4) << 2;  // 0..60
#pragma unroll
      for (int kh = 0; kh < 2; ++kh) {
        int kb = ((tid & 15) << 2) + (kh << 6);
        const short* vp = Vbase + (size_t)(k0 + kb) * 3072 + db;
        short4v r0 = *(const short4v*)(vp);
        short4v r1 = *(const short4v*)(vp + 3072);
        short4v r2 = *(const short4v*)(vp + 2 * 3072);
        short4v r3 = *(const short4v*)(vp + 3 * 3072);
        short4v t0 = {r0.x, r1.x, r2.x, r3.x};
        short4v t1 = {r0.y, r1.y, r2.y, r3.y};
        short4v t2 = {r0.z, r1.z, r2.z, r3.z};
        short4v t3 = {r0.w, r1.w, r2.w, r3.w};
        *(short4v*)&Vt[db + 0][kb] = t0;
        *(short4v*)&Vt[db + 1][kb] = t1;
        *(short4v*)&Vt[db + 2][kb] = t2;
        *(short4v*)&Vt[db + 3][kb] = t3;
      }
    }
    __syncthreads();

    // S^T = K * Q^T  (st[kb][r]: k = k0+kb*16+fg*4+r, q = qcol)
    f32x4 st[8];
#pragma unroll
    for (int kb = 0; kb < 8; ++kb) {
      f32x4 z = {0.f, 0.f, 0.f, 0.f};
      int row = kb * 16 + fr;
      int sw = row & 7;
      bf16x8 kf0 = *(const bf16x8*)&Ks[row][(fg ^ sw) << 3];
      bf16x8 kf1 = *(const bf16x8*)&Ks[row][((4 + fg) ^ sw) << 3];
      z = __builtin_amdgcn_mfma_f32_16x16x32_bf16(kf0, qf[0], z, 0, 0, 0);
      z = __builtin_amdgcn_mfma_f32_16x16x32_bf16(kf1, qf[1], z, 0, 0, 0);
      st[kb] = z;
    }

    // scale + mask + online softmax (base-2 domain, defer-max T13)
    const bool masked = (c == c0);
    float pm = -3.0e38f;
#pragma unroll
    for (int kb = 0; kb < 8; ++kb)
#pragma unroll
      for (int r = 0; r < 4; ++r) {
        float s = st[kb][r] * C2;
        if (masked) {
          int kg = k0 + kb * 16 + fg * 4 + r;
          s = (kg < qcol) ? -3.0e38f : s;
        }
        st[kb][r] = s;
        pm = fmaxf(pm, s);
      }
    pm = fmaxf(pm, __shfl_xor(pm, 16, 64));
    pm = fmaxf(pm, __shfl_xor(pm, 32, 64));

    bool skip = __all(pm - m2 <= 8.0f);
    float mnew = skip ? m2 : fmaxf(m2, pm);
    float psum = 0.f;
#pragma unroll
    for (int kb = 0; kb < 8; ++kb)
#pragma unroll
      for (int r = 0; r < 4; ++r) {
        float e = exp2f(st[kb][r] - mnew);
        st[kb][r] = e;
        psum += e;
      }
    psum += __shfl_xor(psum, 16, 64);
    psum += __shfl_xor(psum, 32, 64);
    if (skip) {
      ls += psum;
    } else {
      float scl = exp2f(m2 - mnew);
      ls = ls * scl + psum;
      m2 = mnew;
#pragma unroll
      for (int r = 0; r < 4; ++r) {
        float so = __shfl(scl, fg * 4 + r, 64);
#pragma unroll
        for (int f = 0; f < 4; ++f) o[f][r] *= so;
      }
    }

    // PV: O[q][d] += P[q][k] V[k][d] via k-permuted 16x16x32 mfma.
    // A slot (fg, j): j<4 -> P[.][kb2*32 + fg*4 + j], j>=4 -> P[.][kb2*32+16+fg*4+j-4]
    // B slot mirrors the same k order from Vt.
#pragma unroll
    for (int kb2 = 0; kb2 < 4; ++kb2) {
      bf16x8 pa = {f2bf(st[2 * kb2][0]),     f2bf(st[2 * kb2][1]),
                   f2bf(st[2 * kb2][2]),     f2bf(st[2 * kb2][3]),
                   f2bf(st[2 * kb2 + 1][0]), f2bf(st[2 * kb2 + 1][1]),
                   f2bf(st[2 * kb2 + 1][2]), f2bf(st[2 * kb2 + 1][3])};
#pragma unroll
      for (int f = 0; f < 4; ++f) {
        short4v v0 = *(const short4v*)&Vt[f * 16 + fr][kb2 * 32 + fg * 4];
        short4v v1 = *(const short4v*)&Vt[f * 16 + fr][kb2 * 32 + 16 + fg * 4];
        bf16x8 vb = {v0.x, v0.y, v0.z, v0.w, v1.x, v1.y, v1.z, v1.w};
        o[f] = __builtin_amdgcn_mfma_f32_16x16x32_bf16(pa, vb, o[f], 0, 0, 0);
      }
    }
    __syncthreads();
  }

  // normalize + store bf16
#pragma unroll
  for (int r = 0; r < 4; ++r) {
    float denom = __shfl(ls, fg * 4 + r, 64);
    float inv = 1.0f / denom;
    size_t orow = rowbase + (size_t)(q0 + w * 16 + fg * 4 + r);
    short* op = outc + orow * 1024 + h * 64 + fr;
#pragma unroll
    for (int f = 0; f < 4; ++f) op[f * 16] = f2bf(o[f][r] * inv);
  }
}

extern "C" void kernel_launch(void* const* d_in, const int* in_sizes, int n_in,
                              void* d_out, int out_size, void* d_ws,
                              size_t ws_size, hipStream_t stream) {
  const float* x = (const float*)d_in[0];
  const float* Wc = (const float*)d_in[1];
  const float* bc = (const float*)d_in[2];
  const float* Wo = (const float*)d_in[3];
  const float* bo = (const float*)d_in[4];
  float* out = (float*)d_out;

  const int Bn = 8, S = 1024, D = 1024;
  const int M = Bn * S;  // 8192

  char* ws = (char*)d_ws;
  short* xb  = (short*)(ws);                               // 16 MB
  short* wct = (short*)(ws + (size_t)16 * 1024 * 1024);    // 6 MB  [3072][1024]
  short* wot = (short*)(ws + (size_t)22 * 1024 * 1024);    // 2 MB  [1024][1024]
  short* qkv = (short*)(ws + (size_t)24 * 1024 * 1024);    // 48 MB [8192][3072]
  short* cat = (short*)(ws + (size_t)72 * 1024 * 1024);    // 16 MB [8192][1024]

  k_f32_to_bf16<<<(M * D / 4 + 255) / 256, 256, 0, stream>>>(x, xb, M * D / 4);
  {
    dim3 g(3 * D / 64, D / 64);
    k_transpose_bf16<<<g, 256, 0, stream>>>(Wc, wct, D, 3 * D);
  }
  {
    dim3 g(D / 64, D / 64);
    k_transpose_bf16<<<g, 256, 0, stream>>>(Wo, wot, D, D);
  }
  k_gemm_bt<false><<<(M / 128) * (3 * D / 128), 256, 0, stream>>>(
      xb, wct, bc, qkv, M, 3 * D, D);
  k_attn<<<16 * 128, 256, 0, stream>>>(qkv, cat, Bn, S);
  k_gemm_bt<true><<<(M / 128) * (D / 128), 256, 0, stream>>>(
      cat, wot, bo, out, M, D, D);
}

// Round 5
// 174.669 us; speedup vs baseline: 1.5533x; 1.1173x over previous
//
#include <hip/hip_runtime.h>
#include <stdint.h>

typedef __attribute__((ext_vector_type(8))) short  bf16x8;
typedef __attribute__((ext_vector_type(4))) short  short4v;
typedef __attribute__((ext_vector_type(4))) float  f32x4;
typedef __attribute__((ext_vector_type(4))) float  float4v;

#define VMW(N) asm volatile("s_waitcnt vmcnt(" #N ")" ::: "memory")
#define BAR()  asm volatile("s_barrier" ::: "memory")

__device__ __forceinline__ short f2bf(float f) {
  union { float f; uint32_t u; } c; c.f = f;
  uint32_t u = c.u;
  uint32_t r = (u + 0x7FFFu + ((u >> 16) & 1u)) >> 16;
  return (short)(uint16_t)r;
}

__device__ __forceinline__ void gload_lds16(const void* g, void* l) {
  __builtin_amdgcn_global_load_lds(
      (const __attribute__((address_space(1))) void*)g,
      (__attribute__((address_space(3))) void*)l, 16, 0, 0);
}

// ---------------- f32 -> bf16 (vectorized, 4 elems/thread) ----------------
__global__ __launch_bounds__(256) void k_f32_to_bf16(
    const float* __restrict__ in, short* __restrict__ out, int n4) {
  int i = blockIdx.x * 256 + threadIdx.x;
  if (i >= n4) return;
  float4v v = *(const float4v*)(in + (size_t)i * 4);
  short4v o;
  o.x = f2bf(v.x); o.y = f2bf(v.y); o.z = f2bf(v.z); o.w = f2bf(v.w);
  *(short4v*)(out + (size_t)i * 4) = o;
}

// ------------- transpose f32[R][C] -> bf16[C][R] (64x64 LDS tiles) -------------
__global__ __launch_bounds__(256) void k_transpose_bf16(
    const float* __restrict__ in, short* __restrict__ out, int R, int C) {
  __shared__ short tile[64][65];
  int bc = blockIdx.x * 64, br = blockIdx.y * 64;
  int tc = threadIdx.x & 63, tr = threadIdx.x >> 6;  // tr 0..3
#pragma unroll
  for (int i = 0; i < 64; i += 4)
    tile[tc][tr + i] = f2bf(in[(size_t)(br + tr + i) * C + bc + tc]);
  __syncthreads();
#pragma unroll
  for (int i = 0; i < 64; i += 4)
    out[(size_t)(bc + tr + i) * R + br + tc] = tile[tr + i][tc];
}

// ------------- GEMM: C[M][N] = A[M][K](bf16) * BT[N][K]^T + bias ---------------
// 128x128 tile, BK=64, 4 waves (2x2), 4-phase counted-vmcnt pipeline (T3+T4),
// K-sliced half-tiles, XOR-swizzled LDS (T2, both-sides), raw s_barrier only.
// Stream of half-tiles per K-tile: [A-k0, B-k0, A-k1, B-k1]; phase p of tile t
// consumes (mh=p&1, kh=p>>1); stage lead = 6 halves; vmcnt(8) steady state.
template <bool F32OUT>
__global__ __launch_bounds__(256) void k_gemm2(
    const short* __restrict__ A, const short* __restrict__ BT,
    const float* __restrict__ bias, void* __restrict__ Cout,
    int M, int N, int K, int nbn) {
  __shared__ short SM[2][2][2][128][32];  // [buf][mat(A=0,B=1)][kh][row][kcol]
  const int tid = threadIdx.x;
  const int w = tid >> 6, l = tid & 63;
  const int fr = l & 15, fg = l >> 4;
  const int wm = w >> 1, wn = w & 1;

  // XCD-bijective swizzle (grid % 8 == 0 for all our launches)
  const int q8 = gridDim.x >> 3;
  const int wg = (blockIdx.x & 7) * q8 + (blockIdx.x >> 3);
  const int bm = wg / nbn, bn = wg % nbn;
  const size_t brow = (size_t)bm << 7;
  const int bcol = bn << 7;

  const int NT = K >> 6;  // 16 for K=1024

  // staging lane addressing: lane l covers (row = r0 + l/4, 16B slot = l&3);
  // source octet pre-swizzled so LDS linear dest holds octet (slot ^ sigma(row))
  const int srow = l >> 2;
  const int soct = (l & 3) ^ ((l >> 3) & 3);
  const short* aG = A + (brow + srow) * (size_t)K + soct * 8;
  const short* bG = BT + ((size_t)(bcol + srow)) * K + soct * 8;

  // fragment read slot (shorts): un-swizzle with same sigma = (fr>>1)&3
  const int slot8 = ((fg ^ ((fr >> 1) & 3)) << 3);

  f32x4 acc[4][4] = {};

  // prologue: stage stream[0..5] = tile0 all 4 halves + tile1 A-k0, B-k0
#pragma unroll
  for (int s = 0; s < 6; ++s) {
    const int t = s >> 2, tau = s & 3, buf = t & 1, mat = tau & 1, kh = tau >> 1;
    const int kbase = t * 64 + kh * 32;
    const short* g0 = (mat ? bG : aG) + kbase;
#pragma unroll
    for (int j = 0; j < 2; ++j) {
      const int r0 = (w * 2 + j) * 16;
      gload_lds16(g0 + (size_t)r0 * K, (char*)&SM[buf][mat][kh][r0][0]);
    }
  }
  VMW(8);   // tile0 k0-halves landed; 4 halves still in flight
  BAR();

  int sidx = 6;
  for (int t = 0; t < NT; ++t) {
    const int buf = t & 1;
#pragma unroll
    for (int p = 0; p < 4; ++p) {
      const int mh = p & 1, kh = p >> 1;
      // ds_read fragments for this quadrant
      bf16x8 af[2], bf[4];
#pragma unroll
      for (int m = 0; m < 2; ++m)
        af[m] = *(const bf16x8*)
            &SM[buf][0][kh][wm * 64 + mh * 32 + m * 16 + fr][slot8];
#pragma unroll
      for (int n = 0; n < 4; ++n)
        bf[n] = *(const bf16x8*)&SM[buf][1][kh][wn * 64 + n * 16 + fr][slot8];
      // stage next half-tile (lead = 6 halves; targets are always dead regions)
      if (sidx < NT * 4) {
        const int ts = sidx >> 2, tau = sidx & 3;
        const int sb = ts & 1, mat = tau & 1, skh = tau >> 1;
        const int kbase = ts * 64 + skh * 32;
        const short* g0 = (mat ? bG : aG) + kbase;
#pragma unroll
        for (int j = 0; j < 2; ++j) {
          const int r0 = (w * 2 + j) * 16;
          gload_lds16(g0 + (size_t)r0 * K, (char*)&SM[sb][mat][skh][r0][0]);
        }
        ++sidx;
      }
      BAR();
      __builtin_amdgcn_s_setprio(1);
#pragma unroll
      for (int m = 0; m < 2; ++m)
#pragma unroll
        for (int n = 0; n < 4; ++n)
          acc[mh * 2 + m][n] = __builtin_amdgcn_mfma_f32_16x16x32_bf16(
              af[m], bf[n], acc[mh * 2 + m][n], 0, 0, 0);
      __builtin_amdgcn_s_setprio(0);
      // counted waits: guard the NEXT quadrant-pair's halves; never 0 mid-loop
      if (p == 1) {
        if (t == NT - 1) { VMW(0); } else { VMW(8); }
      } else if (p == 3 && t < NT - 1) {
        if (t == NT - 2) { VMW(4); } else { VMW(8); }
      }
      BAR();
    }
  }

  // epilogue: bias + store
#pragma unroll
  for (int n = 0; n < 4; ++n) {
    const int col = bcol + wn * 64 + n * 16 + fr;
    const float bv = bias[col];
#pragma unroll
    for (int i = 0; i < 4; ++i) {
      const size_t row = brow + (size_t)(wm * 64 + i * 16 + fg * 4);
#pragma unroll
      for (int r = 0; r < 4; ++r) {
        const float v = acc[i][n][r] + bv;
        if (F32OUT)
          ((float*)Cout)[(row + r) * (size_t)N + col] = v;
        else
          ((short*)Cout)[(row + r) * (size_t)N + col] = f2bf(v);
      }
    }
  }
}

// ---------------- fused anti-causal flash attention (keep k >= q) ----------------
// (unchanged from R4 — verified)
__global__ __launch_bounds__(256) void k_attn(
    const short* __restrict__ qkv, short* __restrict__ outc, int Bn, int S) {
  __shared__ short Ks[128][64];   // 16B slots XOR-swizzled within 128B rows
  __shared__ short Vt[64][136];   // V^T, padded pitch

  const int tid = threadIdx.x;
  const int w = tid >> 6, l = tid & 63;
  const int fr = l & 15, fg = l >> 4;

  const int tq = blockIdx.x >> 7;        // 0..15, longest work first
  const int bh = blockIdx.x & 127;
  const int h = bh & 15, b = bh >> 4;
  const int q0 = tq << 6;

  const size_t rowbase = (size_t)b * S;
  const int qcol = q0 + w * 16 + fr;

  bf16x8 qf[2];
  {
    const short* qp = qkv + (rowbase + qcol) * 3072 + h * 64 + fg * 8;
    qf[0] = *(const bf16x8*)qp;
    qf[1] = *(const bf16x8*)(qp + 32);
  }

  f32x4 o[4] = {};
  float m2 = -3.0e38f, ls = 0.0f;

  const short* Kbase = qkv + rowbase * 3072 + 1024 + h * 64;
  const short* Vbase = qkv + rowbase * 3072 + 2048 + h * 64;
  const float C2 = 0.04508422f;  // log2(e)/sqrt(1024)

  const int c0 = tq >> 1;
  for (int c = c0; c < 8; ++c) {
    const int k0 = c << 7;
    {
      int r8 = l >> 3, slot = l & 7;
#pragma unroll
      for (int j = 0; j < 4; ++j) {
        int ch = w * 4 + j;
        int row = ch * 8 + r8;
        int d = (slot ^ (row & 7)) << 3;
        gload_lds16(Kbase + (size_t)(k0 + row) * 3072 + d,
                    (char*)&Ks[0][0] + ch * 1024);
      }
    }
    {
      int db = (tid >> 4) << 2;
#pragma unroll
      for (int kh = 0; kh < 2; ++kh) {
        int kb = ((tid & 15) << 2) + (kh << 6);
        const short* vp = Vbase + (size_t)(k0 + kb) * 3072 + db;
        short4v r0 = *(const short4v*)(vp);
        short4v r1 = *(const short4v*)(vp + 3072);
        short4v r2 = *(const short4v*)(vp + 2 * 3072);
        short4v r3 = *(const short4v*)(vp + 3 * 3072);
        short4v t0 = {r0.x, r1.x, r2.x, r3.x};
        short4v t1 = {r0.y, r1.y, r2.y, r3.y};
        short4v t2 = {r0.z, r1.z, r2.z, r3.z};
        short4v t3 = {r0.w, r1.w, r2.w, r3.w};
        *(short4v*)&Vt[db + 0][kb] = t0;
        *(short4v*)&Vt[db + 1][kb] = t1;
        *(short4v*)&Vt[db + 2][kb] = t2;
        *(short4v*)&Vt[db + 3][kb] = t3;
      }
    }
    __syncthreads();

    f32x4 st[8];
#pragma unroll
    for (int kb = 0; kb < 8; ++kb) {
      f32x4 z = {0.f, 0.f, 0.f, 0.f};
      int row = kb * 16 + fr;
      int sw = row & 7;
      bf16x8 kf0 = *(const bf16x8*)&Ks[row][(fg ^ sw) << 3];
      bf16x8 kf1 = *(const bf16x8*)&Ks[row][((4 + fg) ^ sw) << 3];
      z = __builtin_amdgcn_mfma_f32_16x16x32_bf16(kf0, qf[0], z, 0, 0, 0);
      z = __builtin_amdgcn_mfma_f32_16x16x32_bf16(kf1, qf[1], z, 0, 0, 0);
      st[kb] = z;
    }

    const bool masked = (c == c0);
    float pm = -3.0e38f;
#pragma unroll
    for (int kb = 0; kb < 8; ++kb)
#pragma unroll
      for (int r = 0; r < 4; ++r) {
        float s = st[kb][r] * C2;
        if (masked) {
          int kg = k0 + kb * 16 + fg * 4 + r;
          s = (kg < qcol) ? -3.0e38f : s;
        }
        st[kb][r] = s;
        pm = fmaxf(pm, s);
      }
    pm = fmaxf(pm, __shfl_xor(pm, 16, 64));
    pm = fmaxf(pm, __shfl_xor(pm, 32, 64));

    bool skip = __all(pm - m2 <= 8.0f);
    float mnew = skip ? m2 : fmaxf(m2, pm);
    float psum = 0.f;
#pragma unroll
    for (int kb = 0; kb < 8; ++kb)
#pragma unroll
      for (int r = 0; r < 4; ++r) {
        float e = exp2f(st[kb][r] - mnew);
        st[kb][r] = e;
        psum += e;
      }
    psum += __shfl_xor(psum, 16, 64);
    psum += __shfl_xor(psum, 32, 64);
    if (skip) {
      ls += psum;
    } else {
      float scl = exp2f(m2 - mnew);
      ls = ls * scl + psum;
      m2 = mnew;
#pragma unroll
      for (int r = 0; r < 4; ++r) {
        float so = __shfl(scl, fg * 4 + r, 64);
#pragma unroll
        for (int f = 0; f < 4; ++f) o[f][r] *= so;
      }
    }

#pragma unroll
    for (int kb2 = 0; kb2 < 4; ++kb2) {
      bf16x8 pa = {f2bf(st[2 * kb2][0]),     f2bf(st[2 * kb2][1]),
                   f2bf(st[2 * kb2][2]),     f2bf(st[2 * kb2][3]),
                   f2bf(st[2 * kb2 + 1][0]), f2bf(st[2 * kb2 + 1][1]),
                   f2bf(st[2 * kb2 + 1][2]), f2bf(st[2 * kb2 + 1][3])};
#pragma unroll
      for (int f = 0; f < 4; ++f) {
        short4v v0 = *(const short4v*)&Vt[f * 16 + fr][kb2 * 32 + fg * 4];
        short4v v1 = *(const short4v*)&Vt[f * 16 + fr][kb2 * 32 + 16 + fg * 4];
        bf16x8 vb = {v0.x, v0.y, v0.z, v0.w, v1.x, v1.y, v1.z, v1.w};
        o[f] = __builtin_amdgcn_mfma_f32_16x16x32_bf16(pa, vb, o[f], 0, 0, 0);
      }
    }
    __syncthreads();
  }

#pragma unroll
  for (int r = 0; r < 4; ++r) {
    float denom = __shfl(ls, fg * 4 + r, 64);
    float inv = 1.0f / denom;
    size_t orow = rowbase + (size_t)(q0 + w * 16 + fg * 4 + r);
    short* op = outc + orow * 1024 + h * 64 + fr;
#pragma unroll
    for (int f = 0; f < 4; ++f) op[f * 16] = f2bf(o[f][r] * inv);
  }
}

extern "C" void kernel_launch(void* const* d_in, const int* in_sizes, int n_in,
                              void* d_out, int out_size, void* d_ws,
                              size_t ws_size, hipStream_t stream) {
  const float* x = (const float*)d_in[0];
  const float* Wc = (const float*)d_in[1];
  const float* bc = (const float*)d_in[2];
  const float* Wo = (const float*)d_in[3];
  const float* bo = (const float*)d_in[4];
  float* out = (float*)d_out;

  const int Bn = 8, S = 1024, D = 1024;
  const int M = Bn * S;  // 8192

  char* ws = (char*)d_ws;
  short* xb  = (short*)(ws);                               // 16 MB
  short* wct = (short*)(ws + (size_t)16 * 1024 * 1024);    // 6 MB  [3072][1024]
  short* wot = (short*)(ws + (size_t)22 * 1024 * 1024);    // 2 MB  [1024][1024]
  short* qkv = (short*)(ws + (size_t)24 * 1024 * 1024);    // 48 MB [8192][3072]
  short* cat = (short*)(ws + (size_t)72 * 1024 * 1024);    // 16 MB [8192][1024]

  k_f32_to_bf16<<<(M * D / 4 + 255) / 256, 256, 0, stream>>>(x, xb, M * D / 4);
  {
    dim3 g(3 * D / 64, D / 64);
    k_transpose_bf16<<<g, 256, 0, stream>>>(Wc, wct, D, 3 * D);
  }
  {
    dim3 g(D / 64, D / 64);
    k_transpose_bf16<<<g, 256, 0, stream>>>(Wo, wot, D, D);
  }
  k_gemm2<false><<<(M / 128) * (3 * D / 128), 256, 0, stream>>>(
      xb, wct, bc, qkv, M, 3 * D, D, 3 * D / 128);
  k_attn<<<16 * 128, 256, 0, stream>>>(qkv, cat, Bn, S);
  k_gemm2<true><<<(M / 128) * (D / 128), 256, 0, stream>>>(
      cat, wot, bo, out, M, D, D, D / 128);
}

// Round 6
// 172.635 us; speedup vs baseline: 1.5716x; 1.0118x over previous
//
#include <hip/hip_runtime.h>
#include <stdint.h>

typedef __attribute__((ext_vector_type(8))) short  bf16x8;
typedef __attribute__((ext_vector_type(4))) short  short4v;
typedef __attribute__((ext_vector_type(4))) float  f32x4;
typedef __attribute__((ext_vector_type(4))) float  float4v;

#define VMW(N) asm volatile("s_waitcnt vmcnt(" #N ")" ::: "memory")
#define BAR()  asm volatile("s_barrier" ::: "memory")

__device__ __forceinline__ short f2bf(float f) {
  union { float f; uint32_t u; } c; c.f = f;
  uint32_t u = c.u;
  uint32_t r = (u + 0x7FFFu + ((u >> 16) & 1u)) >> 16;
  return (short)(uint16_t)r;
}

__device__ __forceinline__ void gload_lds16(const void* g, void* l) {
  __builtin_amdgcn_global_load_lds(
      (const __attribute__((address_space(1))) void*)g,
      (__attribute__((address_space(3))) void*)l, 16, 0, 0);
}

// ---------------- f32 -> bf16 (vectorized, 4 elems/thread) ----------------
__global__ __launch_bounds__(256) void k_f32_to_bf16(
    const float* __restrict__ in, short* __restrict__ out, int n4) {
  int i = blockIdx.x * 256 + threadIdx.x;
  if (i >= n4) return;
  float4v v = *(const float4v*)(in + (size_t)i * 4);
  short4v o;
  o.x = f2bf(v.x); o.y = f2bf(v.y); o.z = f2bf(v.z); o.w = f2bf(v.w);
  *(short4v*)(out + (size_t)i * 4) = o;
}

// ------------- transpose f32[R][C] -> bf16[C][R] (64x64 LDS tiles) -------------
__global__ __launch_bounds__(256) void k_transpose_bf16(
    const float* __restrict__ in, short* __restrict__ out, int R, int C) {
  __shared__ short tile[64][65];
  int bc = blockIdx.x * 64, br = blockIdx.y * 64;
  int tc = threadIdx.x & 63, tr = threadIdx.x >> 6;  // tr 0..3
#pragma unroll
  for (int i = 0; i < 64; i += 4)
    tile[tc][tr + i] = f2bf(in[(size_t)(br + tr + i) * C + bc + tc]);
  __syncthreads();
#pragma unroll
  for (int i = 0; i < 64; i += 4)
    out[(size_t)(bc + tr + i) * R + br + tc] = tile[tr + i][tc];
}

// ------------- GEMM: C[M][N] = A[M][K](bf16) * BT[N][K]^T + bias ---------------
// 128x128 tile, BK=64, 4 waves (2x2), TWO-phase counted-vmcnt pipeline (T3+T4):
// phase kh reads af[4]+bf[4] (8 x b128) and does all 16 MFMA of that K-half.
// Chunk stream per K-tile: [A-k0, B-k0, A-k1, B-k1] (tau 0..3); phase P0 stages
// (t+1, kh1) halves (opposite buffer), P1 stages (t+2, kh0) (same buffer, whose
// kh0 regions were consumed by P0's MFMA before P0's trailing barrier).
// vmcnt: steady 8 (4 chunks in flight), drain 4 -> 0 at the tail. T2 swizzle.
template <bool F32OUT>
__global__ __launch_bounds__(256) void k_gemm2(
    const short* __restrict__ A, const short* __restrict__ BT,
    const float* __restrict__ bias, void* __restrict__ Cout,
    int M, int N, int K, int nbn) {
  __shared__ short SM[2][2][2][128][32];  // [buf][mat(A=0,B=1)][kh][row][kcol]
  const int tid = threadIdx.x;
  const int w = tid >> 6, l = tid & 63;
  const int fr = l & 15, fg = l >> 4;
  const int wm = w >> 1, wn = w & 1;

  // XCD-bijective swizzle (grid % 8 == 0 for all our launches)
  const int q8 = gridDim.x >> 3;
  const int wg = (blockIdx.x & 7) * q8 + (blockIdx.x >> 3);
  const int bm = wg / nbn, bn = wg % nbn;
  const size_t brow = (size_t)bm << 7;
  const int bcol = bn << 7;

  const int NT = K >> 6;  // 16 for K=1024

  // staging lane addressing: lane l covers (row = r0 + l/4, 16B slot = l&3);
  // source octet pre-swizzled so LDS linear dest holds octet (slot ^ sigma(row))
  const int srow = l >> 2;
  const int soct = (l & 3) ^ ((l >> 3) & 3);
  const short* aG = A + (brow + srow) * (size_t)K + soct * 8;
  const short* bG = BT + ((size_t)(bcol + srow)) * K + soct * 8;

  // fragment read slot (shorts): un-swizzle with same sigma = (fr>>1)&3
  const int slot8 = ((fg ^ ((fr >> 1) & 3)) << 3);

  f32x4 acc[4][4] = {};

  // prologue: stage chunks 0..5 = tile0 all 4 halves + tile1 A-k0, B-k0
#pragma unroll
  for (int s = 0; s < 6; ++s) {
    const int t = s >> 2, tau = s & 3, buf = t & 1, mat = tau & 1, kh = tau >> 1;
    const int kbase = t * 64 + kh * 32;
    const short* g0 = (mat ? bG : aG) + kbase;
#pragma unroll
    for (int j = 0; j < 2; ++j) {
      const int r0 = (w * 2 + j) * 16;
      gload_lds16(g0 + (size_t)r0 * K, (char*)&SM[buf][mat][kh][r0][0]);
    }
  }
  VMW(8);   // chunks 0,1 (tile0 kh0) landed; 4 chunks still in flight
  BAR();

  int sidx = 6;
  for (int t = 0; t < NT; ++t) {
    const int buf = t & 1;
#pragma unroll
    for (int p = 0; p < 2; ++p) {
      const int kh = p;
      // stage next 2 chunks (targets: P0 -> other buf kh1; P1 -> this buf kh0,
      // already consumed at P0 and separated by P0's trailing barrier)
#pragma unroll
      for (int s = 0; s < 2; ++s) {
        if (sidx < NT * 4) {
          const int ts = sidx >> 2, tau = sidx & 3;
          const int sb = ts & 1, mat = tau & 1, skh = tau >> 1;
          const int kbase = ts * 64 + skh * 32;
          const short* g0 = (mat ? bG : aG) + kbase;
#pragma unroll
          for (int j = 0; j < 2; ++j) {
            const int r0 = (w * 2 + j) * 16;
            gload_lds16(g0 + (size_t)r0 * K, (char*)&SM[sb][mat][skh][r0][0]);
          }
          ++sidx;
        }
      }
      // read all fragments of this K-half
      bf16x8 af[4], bf[4];
#pragma unroll
      for (int m = 0; m < 4; ++m)
        af[m] = *(const bf16x8*)&SM[buf][0][kh][wm * 64 + m * 16 + fr][slot8];
#pragma unroll
      for (int n = 0; n < 4; ++n)
        bf[n] = *(const bf16x8*)&SM[buf][1][kh][wn * 64 + n * 16 + fr][slot8];
      BAR();
      __builtin_amdgcn_s_setprio(1);
#pragma unroll
      for (int m = 0; m < 4; ++m)
#pragma unroll
        for (int n = 0; n < 4; ++n)
          acc[m][n] = __builtin_amdgcn_mfma_f32_16x16x32_bf16(
              af[m], bf[n], acc[m][n], 0, 0, 0);
      __builtin_amdgcn_s_setprio(0);
      // counted waits (never 0 mid-loop); skip after the very last phase
      if (!(t == NT - 1 && p == 1)) {
        if (t == NT - 1 && p == 0) { VMW(0); }
        else if (t == NT - 2 && p == 1) { VMW(4); }
        else { VMW(8); }
        BAR();
      }
    }
  }

  // epilogue: bias + store
#pragma unroll
  for (int n = 0; n < 4; ++n) {
    const int col = bcol + wn * 64 + n * 16 + fr;
    const float bv = bias[col];
#pragma unroll
    for (int i = 0; i < 4; ++i) {
      const size_t row = brow + (size_t)(wm * 64 + i * 16 + fg * 4);
#pragma unroll
      for (int r = 0; r < 4; ++r) {
        const float v = acc[i][n][r] + bv;
        if (F32OUT)
          ((float*)Cout)[(row + r) * (size_t)N + col] = v;
        else
          ((short*)Cout)[(row + r) * (size_t)N + col] = f2bf(v);
      }
    }
  }
}

// ---------------- fused anti-causal flash attention (keep k >= q) ----------------
// (unchanged from R4/R5 — verified)
__global__ __launch_bounds__(256) void k_attn(
    const short* __restrict__ qkv, short* __restrict__ outc, int Bn, int S) {
  __shared__ short Ks[128][64];   // 16B slots XOR-swizzled within 128B rows
  __shared__ short Vt[64][136];   // V^T, padded pitch

  const int tid = threadIdx.x;
  const int w = tid >> 6, l = tid & 63;
  const int fr = l & 15, fg = l >> 4;

  const int tq = blockIdx.x >> 7;        // 0..15, longest work first
  const int bh = blockIdx.x & 127;
  const int h = bh & 15, b = bh >> 4;
  const int q0 = tq << 6;

  const size_t rowbase = (size_t)b * S;
  const int qcol = q0 + w * 16 + fr;

  bf16x8 qf[2];
  {
    const short* qp = qkv + (rowbase + qcol) * 3072 + h * 64 + fg * 8;
    qf[0] = *(const bf16x8*)qp;
    qf[1] = *(const bf16x8*)(qp + 32);
  }

  f32x4 o[4] = {};
  float m2 = -3.0e38f, ls = 0.0f;

  const short* Kbase = qkv + rowbase * 3072 + 1024 + h * 64;
  const short* Vbase = qkv + rowbase * 3072 + 2048 + h * 64;
  const float C2 = 0.04508422f;  // log2(e)/sqrt(1024)

  const int c0 = tq >> 1;
  for (int c = c0; c < 8; ++c) {
    const int k0 = c << 7;
    {
      int r8 = l >> 3, slot = l & 7;
#pragma unroll
      for (int j = 0; j < 4; ++j) {
        int ch = w * 4 + j;
        int row = ch * 8 + r8;
        int d = (slot ^ (row & 7)) << 3;
        gload_lds16(Kbase + (size_t)(k0 + row) * 3072 + d,
                    (char*)&Ks[0][0] + ch * 1024);
      }
    }
    {
      int db = (tid >> 4) << 2;
#pragma unroll
      for (int kh = 0; kh < 2; ++kh) {
        int kb = ((tid & 15) << 2) + (kh << 6);
        const short* vp = Vbase + (size_t)(k0 + kb) * 3072 + db;
        short4v r0 = *(const short4v*)(vp);
        short4v r1 = *(const short4v*)(vp + 3072);
        short4v r2 = *(const short4v*)(vp + 2 * 3072);
        short4v r3 = *(const short4v*)(vp + 3 * 3072);
        short4v t0 = {r0.x, r1.x, r2.x, r3.x};
        short4v t1 = {r0.y, r1.y, r2.y, r3.y};
        short4v t2 = {r0.z, r1.z, r2.z, r3.z};
        short4v t3 = {r0.w, r1.w, r2.w, r3.w};
        *(short4v*)&Vt[db + 0][kb] = t0;
        *(short4v*)&Vt[db + 1][kb] = t1;
        *(short4v*)&Vt[db + 2][kb] = t2;
        *(short4v*)&Vt[db + 3][kb] = t3;
      }
    }
    __syncthreads();

    f32x4 st[8];
#pragma unroll
    for (int kb = 0; kb < 8; ++kb) {
      f32x4 z = {0.f, 0.f, 0.f, 0.f};
      int row = kb * 16 + fr;
      int sw = row & 7;
      bf16x8 kf0 = *(const bf16x8*)&Ks[row][(fg ^ sw) << 3];
      bf16x8 kf1 = *(const bf16x8*)&Ks[row][((4 + fg) ^ sw) << 3];
      z = __builtin_amdgcn_mfma_f32_16x16x32_bf16(kf0, qf[0], z, 0, 0, 0);
      z = __builtin_amdgcn_mfma_f32_16x16x32_bf16(kf1, qf[1], z, 0, 0, 0);
      st[kb] = z;
    }

    const bool masked = (c == c0);
    float pm = -3.0e38f;
#pragma unroll
    for (int kb = 0; kb < 8; ++kb)
#pragma unroll
      for (int r = 0; r < 4; ++r) {
        float s = st[kb][r] * C2;
        if (masked) {
          int kg = k0 + kb * 16 + fg * 4 + r;
          s = (kg < qcol) ? -3.0e38f : s;
        }
        st[kb][r] = s;
        pm = fmaxf(pm, s);
      }
    pm = fmaxf(pm, __shfl_xor(pm, 16, 64));
    pm = fmaxf(pm, __shfl_xor(pm, 32, 64));

    bool skip = __all(pm - m2 <= 8.0f);
    float mnew = skip ? m2 : fmaxf(m2, pm);
    float psum = 0.f;
#pragma unroll
    for (int kb = 0; kb < 8; ++kb)
#pragma unroll
      for (int r = 0; r < 4; ++r) {
        float e = exp2f(st[kb][r] - mnew);
        st[kb][r] = e;
        psum += e;
      }
    psum += __shfl_xor(psum, 16, 64);
    psum += __shfl_xor(psum, 32, 64);
    if (skip) {
      ls += psum;
    } else {
      float scl = exp2f(m2 - mnew);
      ls = ls * scl + psum;
      m2 = mnew;
#pragma unroll
      for (int r = 0; r < 4; ++r) {
        float so = __shfl(scl, fg * 4 + r, 64);
#pragma unroll
        for (int f = 0; f < 4; ++f) o[f][r] *= so;
      }
    }

#pragma unroll
    for (int kb2 = 0; kb2 < 4; ++kb2) {
      bf16x8 pa = {f2bf(st[2 * kb2][0]),     f2bf(st[2 * kb2][1]),
                   f2bf(st[2 * kb2][2]),     f2bf(st[2 * kb2][3]),
                   f2bf(st[2 * kb2 + 1][0]), f2bf(st[2 * kb2 + 1][1]),
                   f2bf(st[2 * kb2 + 1][2]), f2bf(st[2 * kb2 + 1][3])};
#pragma unroll
      for (int f = 0; f < 4; ++f) {
        short4v v0 = *(const short4v*)&Vt[f * 16 + fr][kb2 * 32 + fg * 4];
        short4v v1 = *(const short4v*)&Vt[f * 16 + fr][kb2 * 32 + 16 + fg * 4];
        bf16x8 vb = {v0.x, v0.y, v0.z, v0.w, v1.x, v1.y, v1.z, v1.w};
        o[f] = __builtin_amdgcn_mfma_f32_16x16x32_bf16(pa, vb, o[f], 0, 0, 0);
      }
    }
    __syncthreads();
  }

#pragma unroll
  for (int r = 0; r < 4; ++r) {
    float denom = __shfl(ls, fg * 4 + r, 64);
    float inv = 1.0f / denom;
    size_t orow = rowbase + (size_t)(q0 + w * 16 + fg * 4 + r);
    short* op = outc + orow * 1024 + h * 64 + fr;
#pragma unroll
    for (int f = 0; f < 4; ++f) op[f * 16] = f2bf(o[f][r] * inv);
  }
}

extern "C" void kernel_launch(void* const* d_in, const int* in_sizes, int n_in,
                              void* d_out, int out_size, void* d_ws,
                              size_t ws_size, hipStream_t stream) {
  const float* x = (const float*)d_in[0];
  const float* Wc = (const float*)d_in[1];
  const float* bc = (const float*)d_in[2];
  const float* Wo = (const float*)d_in[3];
  const float* bo = (const float*)d_in[4];
  float* out = (float*)d_out;

  const int Bn = 8, S = 1024, D = 1024;
  const int M = Bn * S;  // 8192

  char* ws = (char*)d_ws;
  short* xb  = (short*)(ws);                               // 16 MB
  short* wct = (short*)(ws + (size_t)16 * 1024 * 1024);    // 6 MB  [3072][1024]
  short* wot = (short*)(ws + (size_t)22 * 1024 * 1024);    // 2 MB  [1024][1024]
  short* qkv = (short*)(ws + (size_t)24 * 1024 * 1024);    // 48 MB [8192][3072]
  short* cat = (short*)(ws + (size_t)72 * 1024 * 1024);    // 16 MB [8192][1024]

  k_f32_to_bf16<<<(M * D / 4 + 255) / 256, 256, 0, stream>>>(x, xb, M * D / 4);
  {
    dim3 g(3 * D / 64, D / 64);
    k_transpose_bf16<<<g, 256, 0, stream>>>(Wc, wct, D, 3 * D);
  }
  {
    dim3 g(D / 64, D / 64);
    k_transpose_bf16<<<g, 256, 0, stream>>>(Wo, wot, D, D);
  }
  k_gemm2<false><<<(M / 128) * (3 * D / 128), 256, 0, stream>>>(
      xb, wct, bc, qkv, M, 3 * D, D, 3 * D / 128);
  k_attn<<<16 * 128, 256, 0, stream>>>(qkv, cat, Bn, S);
  k_gemm2<true><<<(M / 128) * (D / 128), 256, 0, stream>>>(
      cat, wot, bo, out, M, D, D, D / 128);
}